// Round 2
// baseline (1515.686 us; speedup 1.0000x reference)
//
#include <hip/hip_runtime.h>
#include <math.h>

#define NN   100000
#define EE   1600000
#define ET   (EE + NN)          // edges + self-loops = 1,700,000
#define HID  64
#define MLPH 128
#define ODIM 74
#define SLOPE 0.2f

// ---------------- helpers ----------------

__device__ __forceinline__ void atomicMaxF(float* addr, float v) {
    // monotonic-bits trick: int compare for >=0, uint-min for <0. Init must be -inf.
    if (v >= 0.f) atomicMax((int*)addr, __float_as_int(v));
    else          atomicMin((unsigned int*)addr, __float_as_uint(v));
}

// ---------------- kernels ----------------

// h = x @ W  (IN_DIM=3), plus per-node hs = h.a_src, hd = h.a_dst (wave reduce).
// grid 25000 x 256 (4 nodes/block, 1 wave/node, lane = feature)
__global__ void k_lin1(const float* __restrict__ x, const float* __restrict__ W,
                       const float* __restrict__ asrc, const float* __restrict__ adst,
                       float* __restrict__ h, float* __restrict__ hs, float* __restrict__ hd) {
    int node = blockIdx.x * 4 + (threadIdx.x >> 6);
    int f    = threadIdx.x & 63;
    float x0 = x[node*3+0], x1 = x[node*3+1], x2 = x[node*3+2];
    float v  = x0*W[f] + x1*W[64+f] + x2*W[128+f];
    h[node*64+f] = v;
    float ps = v*asrc[f], pd = v*adst[f];
    #pragma unroll
    for (int o = 32; o > 0; o >>= 1) { ps += __shfl_down(ps, o); pd += __shfl_down(pd, o); }
    if (f == 0) { hs[node] = ps; hd[node] = pd; }
}

// init acc to 0, m to -inf, s to 0 (ws is poisoned 0xAA before every call)
__global__ void k_init(float* __restrict__ acc, float* __restrict__ m, float* __restrict__ s) {
    int stride = gridDim.x * blockDim.x;
    for (int i = blockIdx.x*blockDim.x + threadIdx.x; i < NN*HID; i += stride) {
        acc[i] = 0.f;
        if (i < NN) { m[i] = -INFINITY; s[i] = 0.f; }
    }
}

// per edge: e = leaky_relu(hs[src]+hd[dst]); store; atomicMax m[dst]
__global__ void k_edge_score(const int* __restrict__ esrc, const int* __restrict__ edst,
                             const float* __restrict__ hs, const float* __restrict__ hd,
                             float* __restrict__ ebuf, float* __restrict__ m) {
    int i = blockIdx.x*blockDim.x + threadIdx.x;
    if (i >= ET) return;
    int s_ = (i < EE) ? esrc[i] : (i - EE);
    int d_ = (i < EE) ? edst[i] : (i - EE);
    float e = hs[s_] + hd[d_];
    e = (e > 0.f) ? e : SLOPE*e;
    ebuf[i] = e;
    atomicMaxF(&m[d_], e);
}

// per edge: p = exp(e - m[dst]); store p over e; atomicAdd s[dst]
__global__ void k_edge_exp(const int* __restrict__ edst,
                           const float* __restrict__ m, float* __restrict__ ebuf,
                           float* __restrict__ s) {
    int i = blockIdx.x*blockDim.x + threadIdx.x;
    if (i >= ET) return;
    int d_ = (i < EE) ? edst[i] : (i - EE);
    float p = expf(ebuf[i] - m[d_]);
    ebuf[i] = p;
    atomicAdd(&s[d_], p);
}

// one wave per edge, lane = feature: acc[dst][f] += (p/s[dst]) * h[src][f]
// grid 425000 x 256 (4 edges/block)
__global__ void k_edge_agg(const int* __restrict__ esrc, const int* __restrict__ edst,
                           const float* __restrict__ ebuf, const float* __restrict__ s,
                           const float* __restrict__ h, float* __restrict__ acc) {
    int i    = blockIdx.x * 4 + (threadIdx.x >> 6);
    int lane = threadIdx.x & 63;
    if (i >= ET) return;
    int s_ = (i < EE) ? esrc[i] : (i - EE);
    int d_ = (i < EE) ? edst[i] : (i - EE);
    float alpha = ebuf[i] / s[d_];
    atomicAdd(&acc[d_*64 + lane], alpha * h[s_*64 + lane]);
}

// x = relu(acc + b)   (in place), grid 25000 x 256
__global__ void k_bias_relu(float* __restrict__ acc, const float* __restrict__ b) {
    int i = blockIdx.x*blockDim.x + threadIdx.x;
    acc[i] = fmaxf(acc[i] + b[i & 63], 0.f);
}

// h = xin @ W (64x64), plus hs/hd reductions. 4 nodes/block, LDS row stage.
__global__ void k_lin64(const float* __restrict__ xin, const float* __restrict__ W,
                        const float* __restrict__ asrc, const float* __restrict__ adst,
                        float* __restrict__ h, float* __restrict__ hs, float* __restrict__ hd) {
    __shared__ float xr[4][64];
    int w = threadIdx.x >> 6;
    int f = threadIdx.x & 63;
    int node = blockIdx.x * 4 + w;
    xr[w][f] = xin[node*64 + f];
    __syncthreads();
    float acc = 0.f;
    #pragma unroll
    for (int k = 0; k < 64; ++k) acc += xr[w][k] * W[k*64 + f];
    h[node*64 + f] = acc;
    float ps = acc*asrc[f], pd = acc*adst[f];
    #pragma unroll
    for (int o = 32; o > 0; o >>= 1) { ps += __shfl_down(ps, o); pd += __shfl_down(pd, o); }
    if (f == 0) { hs[node] = ps; hd[node] = pd; }
}

// fused MLP head: hid = relu(x@Wp1+bp1) [128]; out = hid@Wp2+bp2 [74]
// one node per 128-thread block
__global__ void k_mlp(const float* __restrict__ xin,
                      const float* __restrict__ Wp1, const float* __restrict__ bp1,
                      const float* __restrict__ Wp2, const float* __restrict__ bp2,
                      float* __restrict__ out) {
    __shared__ float xr[64];
    __shared__ float hid[MLPH];
    int n = blockIdx.x;
    int t = threadIdx.x;
    if (t < 64) xr[t] = xin[n*64 + t];
    __syncthreads();
    float a = bp1[t];
    #pragma unroll
    for (int k = 0; k < 64; ++k) a += xr[k] * Wp1[k*MLPH + t];
    hid[t] = fmaxf(a, 0.f);
    __syncthreads();
    if (t < ODIM) {
        float o = bp2[t];
        #pragma unroll
        for (int j = 0; j < MLPH; ++j) o += hid[j] * Wp2[j*ODIM + t];
        out[n*ODIM + t] = o;
    }
}

// ---------------- launch ----------------

extern "C" void kernel_launch(void* const* d_in, const int* in_sizes, int n_in,
                              void* d_out, int out_size, void* d_ws, size_t ws_size,
                              hipStream_t stream) {
    const float* x    = (const float*)d_in[0];
    const int*   ei   = (const int*)  d_in[1];
    const float* W1   = (const float*)d_in[2];
    const float* a1s  = (const float*)d_in[3];
    const float* a1d  = (const float*)d_in[4];
    const float* b1   = (const float*)d_in[5];
    const float* W2   = (const float*)d_in[6];
    const float* a2s  = (const float*)d_in[7];
    const float* a2d  = (const float*)d_in[8];
    const float* b2   = (const float*)d_in[9];
    const float* Wp1  = (const float*)d_in[10];
    const float* bp1  = (const float*)d_in[11];
    const float* Wp2  = (const float*)d_in[12];
    const float* bp2  = (const float*)d_in[13];
    float* out = (float*)d_out;

    const int* esrc = ei;
    const int* edst = ei + EE;

    float* ws   = (float*)d_ws;
    float* bufA = ws;                      // h (N*64)
    float* bufB = bufA + NN*HID;           // acc1/x2, later acc2/x3 (N*64)
    float* hs   = bufB + NN*HID;           // N
    float* hd   = hs + NN;                 // N
    float* m    = hd + NN;                 // N
    float* s    = m  + NN;                 // N
    float* ebuf = s  + NN;                 // ET

    const int EB = (ET + 255) / 256;       // 6641

    // ---- GAT layer 1 ----
    k_lin1<<<NN/4, 256, 0, stream>>>(x, W1, a1s, a1d, bufA, hs, hd);
    k_init<<<4096, 256, 0, stream>>>(bufB, m, s);
    k_edge_score<<<EB, 256, 0, stream>>>(esrc, edst, hs, hd, ebuf, m);
    k_edge_exp<<<EB, 256, 0, stream>>>(edst, m, ebuf, s);
    k_edge_agg<<<ET/4, 256, 0, stream>>>(esrc, edst, ebuf, s, bufA, bufB);
    k_bias_relu<<<NN*HID/256, 256, 0, stream>>>(bufB, b1);      // bufB = x2

    // ---- GAT layer 2 ----
    k_lin64<<<NN/4, 256, 0, stream>>>(bufB, W2, a2s, a2d, bufA, hs, hd); // bufA = h2
    k_init<<<4096, 256, 0, stream>>>(bufB, m, s);               // bufB now acc2 (x2 consumed)
    k_edge_score<<<EB, 256, 0, stream>>>(esrc, edst, hs, hd, ebuf, m);
    k_edge_exp<<<EB, 256, 0, stream>>>(edst, m, ebuf, s);
    k_edge_agg<<<ET/4, 256, 0, stream>>>(esrc, edst, ebuf, s, bufA, bufB);
    k_bias_relu<<<NN*HID/256, 256, 0, stream>>>(bufB, b2);      // bufB = x3

    // ---- MLP head ----
    k_mlp<<<NN, MLPH, 0, stream>>>(bufB, Wp1, bp1, Wp2, bp2, out);
}

// Round 3
// 790.936 us; speedup vs baseline: 1.9163x; 1.9163x over previous
//
#include <hip/hip_runtime.h>
#include <math.h>

#define NN   100000
#define EE   1600000
#define ET   (EE + NN)          // edges + self-loops = 1,700,000
#define HID  64
#define MLPH 128
#define ODIM 74
#define SLOPE 0.2f
#define NB_SCAN 196             // ceil(NN/512)

// ---------------- CSR build ----------------

__global__ void k_zero(int* __restrict__ deg) {
    int i = blockIdx.x*blockDim.x + threadIdx.x;
    if (i < NN) deg[i] = 0;
}

__global__ void k_hist(const int* __restrict__ edst, int* __restrict__ deg) {
    int i = blockIdx.x*blockDim.x + threadIdx.x;
    if (i >= ET) return;
    int d_ = (i < EE) ? edst[i] : (i - EE);
    atomicAdd(&deg[d_], 1);
}

// per-block exclusive scan: excl[g] = sum of deg[block_start..g-1]; partial[b] = block total
__global__ void k_scan_local(const int* __restrict__ deg, int* __restrict__ excl,
                             int* __restrict__ partial) {
    __shared__ int sd[512];
    int g = blockIdx.x*512 + threadIdx.x;
    int v = (g < NN) ? deg[g] : 0;
    sd[threadIdx.x] = v;
    __syncthreads();
    for (int o = 1; o < 512; o <<= 1) {
        int u = (threadIdx.x >= o) ? sd[threadIdx.x - o] : 0;
        __syncthreads();
        sd[threadIdx.x] += u;
        __syncthreads();
    }
    if (g < NN) excl[g] = sd[threadIdx.x] - v;     // exclusive within block
    if (threadIdx.x == 511) partial[blockIdx.x] = sd[511];
}

// single-block inclusive scan of the NB_SCAN partials
__global__ void k_scan_part(int* __restrict__ partial) {
    __shared__ int sp[256];
    int t = threadIdx.x;
    int v = (t < NB_SCAN) ? partial[t] : 0;
    sp[t] = v;
    __syncthreads();
    for (int o = 1; o < 256; o <<= 1) {
        int u = (t >= o) ? sp[t - o] : 0;
        __syncthreads();
        sp[t] += u;
        __syncthreads();
    }
    if (t < NB_SCAN) partial[t] = sp[t];
}

// excl[g] += block offset;  cursor[g] = excl[g] (scatter cursors; after scatter cursor[n]==row end)
__global__ void k_scan_fin(int* __restrict__ excl, const int* __restrict__ partial,
                           int* __restrict__ cursor) {
    int g = blockIdx.x*512 + threadIdx.x;
    if (g >= NN) return;
    int off = (blockIdx.x > 0) ? partial[blockIdx.x - 1] : 0;
    int e = excl[g] + off;
    excl[g] = e;
    cursor[g] = e;
}

__global__ void k_scatter(const int* __restrict__ esrc, const int* __restrict__ edst,
                          int* __restrict__ cursor, int* __restrict__ col) {
    int i = blockIdx.x*blockDim.x + threadIdx.x;
    if (i >= ET) return;
    int s_ = (i < EE) ? esrc[i] : (i - EE);
    int d_ = (i < EE) ? edst[i] : (i - EE);
    int pos = atomicAdd(&cursor[d_], 1);
    col[pos] = s_;
}

// ---------------- dense prologues ----------------

// h = x @ W  (IN_DIM=3) + per-node hs = h.a_src, hd = h.a_dst
__global__ void k_lin1(const float* __restrict__ x, const float* __restrict__ W,
                       const float* __restrict__ asrc, const float* __restrict__ adst,
                       float* __restrict__ h, float* __restrict__ hs, float* __restrict__ hd) {
    int node = blockIdx.x * 4 + (threadIdx.x >> 6);
    int f    = threadIdx.x & 63;
    float x0 = x[node*3+0], x1 = x[node*3+1], x2 = x[node*3+2];
    float v  = x0*W[f] + x1*W[64+f] + x2*W[128+f];
    h[node*64+f] = v;
    float ps = v*asrc[f], pd = v*adst[f];
    #pragma unroll
    for (int o = 32; o > 0; o >>= 1) { ps += __shfl_down(ps, o); pd += __shfl_down(pd, o); }
    if (f == 0) { hs[node] = ps; hd[node] = pd; }
}

// h = xin @ W (64x64) + hs/hd
__global__ void k_lin64(const float* __restrict__ xin, const float* __restrict__ W,
                        const float* __restrict__ asrc, const float* __restrict__ adst,
                        float* __restrict__ h, float* __restrict__ hs, float* __restrict__ hd) {
    __shared__ float xr[4][64];
    int w = threadIdx.x >> 6;
    int f = threadIdx.x & 63;
    int node = blockIdx.x * 4 + w;
    xr[w][f] = xin[node*64 + f];
    __syncthreads();
    float acc = 0.f;
    #pragma unroll
    for (int k = 0; k < 64; ++k) acc += xr[w][k] * W[k*64 + f];
    h[node*64 + f] = acc;
    float ps = acc*asrc[f], pd = acc*adst[f];
    #pragma unroll
    for (int o = 32; o > 0; o >>= 1) { ps += __shfl_down(ps, o); pd += __shfl_down(pd, o); }
    if (f == 0) { hs[node] = ps; hd[node] = pd; }
}

// ---------------- fused GAT aggregate: one wave per dst node ----------------
// softmax over incoming edges + alpha-weighted gather + bias + relu, no atomics.
__global__ void k_gat(const int* __restrict__ rowbeg, const int* __restrict__ rowend,
                      const int* __restrict__ col,
                      const float* __restrict__ hs, const float* __restrict__ hd,
                      const float* __restrict__ h, const float* __restrict__ bias,
                      float* __restrict__ out) {
    __shared__ float se[4][128];
    int w    = threadIdx.x >> 6;
    int lane = threadIdx.x & 63;
    int n    = blockIdx.x * 4 + w;
    float* e = se[w];

    int base = rowbeg[n];
    int d    = rowend[n] - base;          // >=1 (self-loop)
    float hdn = hd[n];

    // phase A1: scores + wave max
    float mymax = -INFINITY;
    for (int k = lane; k < d; k += 64) {
        float sc = hs[col[base + k]] + hdn;
        sc = (sc > 0.f) ? sc : SLOPE * sc;
        if (k < 128) e[k] = sc;
        mymax = fmaxf(mymax, sc);
    }
    #pragma unroll
    for (int o = 32; o > 0; o >>= 1) mymax = fmaxf(mymax, __shfl_xor(mymax, o));

    // phase A2: exp + wave sum (own elements only; no cross-lane reads yet)
    float mysum = 0.f;
    for (int k = lane; k < d; k += 64) {
        float sc;
        if (k < 128) sc = e[k];
        else {
            sc = hs[col[base + k]] + hdn;
            sc = (sc > 0.f) ? sc : SLOPE * sc;
        }
        float p = expf(sc - mymax);
        if (k < 128) e[k] = p;
        mysum += p;
    }
    #pragma unroll
    for (int o = 32; o > 0; o >>= 1) mysum += __shfl_xor(mysum, o);
    float inv = 1.f / mysum;

    __syncthreads();   // publish p values for cross-lane reads

    // phase B: acc[f] += alpha_k * h[src_k][f]   (lane = feature, coalesced 256B rows)
    float accf = 0.f;
    for (int k = 0; k < d; ++k) {
        float p;
        if (k < 128) p = e[k];
        else {
            float sc = hs[col[base + k]] + hdn;
            sc = (sc > 0.f) ? sc : SLOPE * sc;
            p = expf(sc - mymax);
        }
        int src = col[base + k];
        accf += (p * inv) * h[src*64 + lane];
    }
    out[n*64 + lane] = fmaxf(accf + bias[lane], 0.f);
}

// ---------------- MLP head: 32 nodes/block, weights staged in LDS ----------------
__global__ void k_mlp(const float* __restrict__ xin,
                      const float* __restrict__ Wp1, const float* __restrict__ bp1,
                      const float* __restrict__ Wp2, const float* __restrict__ bp2,
                      float* __restrict__ out) {
    __shared__ float xr[32][64];        // 8 KB
    __shared__ float hid[32][128];      // 16 KB
    __shared__ float wbuf[MLPH*ODIM];   // 37 KB (holds Wp1 [8192] then Wp2 [9472])
    int t    = threadIdx.x;             // 0..255
    int o1   = t & 127;
    int half = t >> 7;

    // stage x rows + Wp1
    for (int i = t; i < 32*64; i += 256) xr[i >> 6][i & 63] = xin[blockIdx.x*(32*64) + i];
    for (int i = t; i < 64*MLPH; i += 256) wbuf[i] = Wp1[i];
    __syncthreads();

    // phase 1: hid = relu(x @ Wp1 + bp1); each thread: 16 nodes x 1 hidden unit
    float acc[16];
    float b1v = bp1[o1];
    #pragma unroll
    for (int ni = 0; ni < 16; ++ni) acc[ni] = b1v;
    for (int k = 0; k < 64; ++k) {
        float wk = wbuf[k*MLPH + o1];
        #pragma unroll
        for (int ni = 0; ni < 16; ++ni) acc[ni] += xr[half*16 + ni][k] * wk;
    }
    #pragma unroll
    for (int ni = 0; ni < 16; ++ni) hid[half*16 + ni][o1] = fmaxf(acc[ni], 0.f);
    __syncthreads();

    // stage Wp2 over the same buffer
    for (int i = t; i < MLPH*ODIM; i += 256) wbuf[i] = Wp2[i];
    __syncthreads();

    // phase 2: out = hid @ Wp2 + bp2; threads with o1 < 74 each do 16 nodes
    if (o1 < ODIM) {
        float b2v = bp2[o1];
        float acc2[16];
        #pragma unroll
        for (int ni = 0; ni < 16; ++ni) acc2[ni] = b2v;
        for (int j = 0; j < MLPH; ++j) {
            float w2 = wbuf[j*ODIM + o1];
            #pragma unroll
            for (int ni = 0; ni < 16; ++ni) acc2[ni] += hid[half*16 + ni][j] * w2;
        }
        #pragma unroll
        for (int ni = 0; ni < 16; ++ni)
            out[(blockIdx.x*32 + half*16 + ni)*ODIM + o1] = acc2[ni];
    }
}

// ---------------- launch ----------------

extern "C" void kernel_launch(void* const* d_in, const int* in_sizes, int n_in,
                              void* d_out, int out_size, void* d_ws, size_t ws_size,
                              hipStream_t stream) {
    const float* x    = (const float*)d_in[0];
    const int*   ei   = (const int*)  d_in[1];
    const float* W1   = (const float*)d_in[2];
    const float* a1s  = (const float*)d_in[3];
    const float* a1d  = (const float*)d_in[4];
    const float* b1   = (const float*)d_in[5];
    const float* W2   = (const float*)d_in[6];
    const float* a2s  = (const float*)d_in[7];
    const float* a2d  = (const float*)d_in[8];
    const float* b2   = (const float*)d_in[9];
    const float* Wp1  = (const float*)d_in[10];
    const float* bp1  = (const float*)d_in[11];
    const float* Wp2  = (const float*)d_in[12];
    const float* bp2  = (const float*)d_in[13];
    float* out = (float*)d_out;

    const int* esrc = ei;
    const int* edst = ei + EE;

    float* ws   = (float*)d_ws;
    float* bufA = ws;                      // h (N*64)
    float* bufB = bufA + NN*HID;           // layer outputs (N*64)
    float* hs   = bufB + NN*HID;           // N
    float* hd   = hs + NN;                 // N
    int*   deg    = (int*)(hd + NN);       // N
    int*   excl   = deg + NN;              // N  (row begin)
    int*   cursor = excl + NN;             // N  (scatter cursor -> row end)
    int*   partial= cursor + NN;           // 256
    int*   col    = partial + 256;         // ET

    const int EB = (ET + 255) / 256;       // 6641

    // ---- CSR build (shared by both layers) ----
    k_zero      <<<(NN+255)/256, 256, 0, stream>>>(deg);
    k_hist      <<<EB, 256, 0, stream>>>(edst, deg);
    k_scan_local<<<NB_SCAN, 512, 0, stream>>>(deg, excl, partial);
    k_scan_part <<<1, 256, 0, stream>>>(partial);
    k_scan_fin  <<<NB_SCAN, 512, 0, stream>>>(excl, partial, cursor);
    k_scatter   <<<EB, 256, 0, stream>>>(esrc, edst, cursor, col);

    // ---- GAT layer 1 ----
    k_lin1<<<NN/4, 256, 0, stream>>>(x, W1, a1s, a1d, bufA, hs, hd);
    k_gat <<<NN/4, 256, 0, stream>>>(excl, cursor, col, hs, hd, bufA, b1, bufB);

    // ---- GAT layer 2 ----
    k_lin64<<<NN/4, 256, 0, stream>>>(bufB, W2, a2s, a2d, bufA, hs, hd);
    k_gat  <<<NN/4, 256, 0, stream>>>(excl, cursor, col, hs, hd, bufA, b2, bufB);

    // ---- MLP head ----
    k_mlp<<<NN/32, 256, 0, stream>>>(bufB, Wp1, bp1, Wp2, bp2, out);
}

// Round 4
// 595.785 us; speedup vs baseline: 2.5440x; 1.3276x over previous
//
#include <hip/hip_runtime.h>
#include <math.h>

#define NN   100000
#define EE   1600000
#define ET   (EE + NN)          // edges + self-loops = 1,700,000
#define HID  64
#define MLPH 128
#define ODIM 74
#define SLOPE 0.2f
#define NB_SCAN 196             // ceil(NN/512)

__device__ __forceinline__ float f4get(const float4& v, int i) {
    return i == 0 ? v.x : i == 1 ? v.y : i == 2 ? v.z : v.w;  // unrolled -> constant
}

// ---------------- CSR build (self-loop pre-placed) ----------------

__global__ void k_deg_init(int* __restrict__ deg) {
    int i = blockIdx.x*blockDim.x + threadIdx.x;
    if (i < NN) deg[i] = 1;                     // self-loop
}

__global__ void k_hist(const int* __restrict__ edst, int* __restrict__ deg) {
    int i = blockIdx.x*blockDim.x + threadIdx.x;
    if (i < EE) atomicAdd(&deg[edst[i]], 1);
}

// per-block exclusive scan
__global__ void k_scan_local(const int* __restrict__ deg, int* __restrict__ excl,
                             int* __restrict__ partial) {
    __shared__ int sd[512];
    int g = blockIdx.x*512 + threadIdx.x;
    int v = (g < NN) ? deg[g] : 0;
    sd[threadIdx.x] = v;
    __syncthreads();
    for (int o = 1; o < 512; o <<= 1) {
        int u = (threadIdx.x >= o) ? sd[threadIdx.x - o] : 0;
        __syncthreads();
        sd[threadIdx.x] += u;
        __syncthreads();
    }
    if (g < NN) excl[g] = sd[threadIdx.x] - v;
    if (threadIdx.x == 511) partial[blockIdx.x] = sd[511];
}

__global__ void k_scan_part(int* __restrict__ partial) {
    __shared__ int sp[256];
    int t = threadIdx.x;
    int v = (t < NB_SCAN) ? partial[t] : 0;
    sp[t] = v;
    __syncthreads();
    for (int o = 1; o < 256; o <<= 1) {
        int u = (t >= o) ? sp[t - o] : 0;
        __syncthreads();
        sp[t] += u;
        __syncthreads();
    }
    if (t < NB_SCAN) partial[t] = sp[t];
}

// finalize row starts; write self-loop at row head; cursor points past it
__global__ void k_scan_fin(int* __restrict__ excl, const int* __restrict__ partial,
                           int* __restrict__ cursor, int* __restrict__ col) {
    int g = blockIdx.x*512 + threadIdx.x;
    if (g >= NN) return;
    int off = (blockIdx.x > 0) ? partial[blockIdx.x - 1] : 0;
    int e = excl[g] + off;
    excl[g] = e;
    col[e] = g;                                 // self-loop first in row
    cursor[g] = e + 1;
}

__global__ void k_scatter(const int* __restrict__ esrc, const int* __restrict__ edst,
                          int* __restrict__ cursor, int* __restrict__ col) {
    int i = blockIdx.x*blockDim.x + threadIdx.x;
    if (i >= EE) return;
    int pos = atomicAdd(&cursor[edst[i]], 1);
    col[pos] = esrc[i];
}

// ---------------- dense prologues ----------------

// h = x @ W1 (IN_DIM=3) + hs/hd wave reductions
__global__ void k_lin1(const float* __restrict__ x, const float* __restrict__ W,
                       const float* __restrict__ asrc, const float* __restrict__ adst,
                       float* __restrict__ h, float* __restrict__ hs, float* __restrict__ hd) {
    int node = blockIdx.x * 4 + (threadIdx.x >> 6);
    int f    = threadIdx.x & 63;
    float x0 = x[node*3+0], x1 = x[node*3+1], x2 = x[node*3+2];
    float v  = x0*W[f] + x1*W[64+f] + x2*W[128+f];
    h[node*64+f] = v;
    float ps = v*asrc[f], pd = v*adst[f];
    #pragma unroll
    for (int o = 32; o > 0; o >>= 1) { ps += __shfl_down(ps, o); pd += __shfl_down(pd, o); }
    if (f == 0) { hs[node] = ps; hd[node] = pd; }
}

// h = xin @ W (64x64): 32 nodes/block, 128 threads, 4x4 tile/thread, LDS-staged W
__global__ __launch_bounds__(128) void k_lin64(
        const float* __restrict__ xin, const float* __restrict__ W,
        const float* __restrict__ asrc, const float* __restrict__ adst,
        float* __restrict__ h, float* __restrict__ hs, float* __restrict__ hd) {
    __shared__ float xr[32][64];     // 8 KB (x rows, later reused for h rows)
    __shared__ float wl[64*64];      // 16 KB, [k][o] layout
    int t  = threadIdx.x;
    int nb = blockIdx.x * 32;
    for (int i = t; i < 32*64; i += 128) xr[i >> 6][i & 63] = xin[nb*64 + i];
    for (int i = t; i < 64*64;  i += 128) wl[i] = W[i];
    __syncthreads();

    int nq = t >> 4;    // 0..7 (4 nodes each)
    int hq = t & 15;    // 0..15 (4 outs each)
    float acc[4][4] = {};
    for (int k = 0; k < 64; k += 4) {
        float4 xv[4];
        #pragma unroll
        for (int ni = 0; ni < 4; ++ni) xv[ni] = *(const float4*)&xr[nq*4+ni][k];
        #pragma unroll
        for (int kk = 0; kk < 4; ++kk) {
            float4 wv = *(const float4*)&wl[(k+kk)*64 + hq*4];
            #pragma unroll
            for (int ni = 0; ni < 4; ++ni) {
                float xs = f4get(xv[ni], kk);
                acc[ni][0] += xs*wv.x; acc[ni][1] += xs*wv.y;
                acc[ni][2] += xs*wv.z; acc[ni][3] += xs*wv.w;
            }
        }
    }
    float4 res[4];
    #pragma unroll
    for (int ni = 0; ni < 4; ++ni) {
        res[ni] = make_float4(acc[ni][0], acc[ni][1], acc[ni][2], acc[ni][3]);
        *(float4*)&h[(size_t)(nb + nq*4 + ni)*64 + hq*4] = res[ni];
    }
    __syncthreads();                 // all xr reads done
    #pragma unroll
    for (int ni = 0; ni < 4; ++ni) *(float4*)&xr[nq*4+ni][hq*4] = res[ni];
    __syncthreads();

    // hs/hd: 2 waves x 16 nodes, lane = feature
    int wv_  = t >> 6;
    int lane = t & 63;
    for (int ni = 0; ni < 16; ++ni) {
        int node = wv_*16 + ni;
        float v  = xr[node][lane];
        float ps = v*asrc[lane], pd = v*adst[lane];
        #pragma unroll
        for (int o = 32; o > 0; o >>= 1) { ps += __shfl_down(ps, o); pd += __shfl_down(pd, o); }
        if (lane == 0) { hs[nb+node] = ps; hd[nb+node] = pd; }
    }
}

// ---------------- fused GAT aggregate: one wave per dst node ----------------
__global__ void k_gat(const int* __restrict__ rowbeg, const int* __restrict__ rowend,
                      const int* __restrict__ col,
                      const float* __restrict__ hs, const float* __restrict__ hd,
                      const float* __restrict__ h, const float* __restrict__ bias,
                      float* __restrict__ out) {
    __shared__ float se[4][128];
    __shared__ int   sc[4][128];
    int w    = threadIdx.x >> 6;
    int lane = threadIdx.x & 63;
    int n    = blockIdx.x * 4 + w;
    float* e_ = se[w];
    int*   c_ = sc[w];

    int base = rowbeg[n];
    int d    = rowend[n] - base;          // >=1 (self-loop)
    float hdn = hd[n];

    // phase A1: scores (+ stash col) + wave max
    float mymax = -INFINITY;
    for (int k = lane; k < d; k += 64) {
        int s = col[base + k];
        float scv = hs[s] + hdn;
        scv = (scv > 0.f) ? scv : SLOPE * scv;
        if (k < 128) { e_[k] = scv; c_[k] = s; }
        mymax = fmaxf(mymax, scv);
    }
    #pragma unroll
    for (int o = 32; o > 0; o >>= 1) mymax = fmaxf(mymax, __shfl_xor(mymax, o));

    // phase A2: exp + wave sum (own elements only)
    float mysum = 0.f;
    for (int k = lane; k < d; k += 64) {
        float scv;
        if (k < 128) scv = e_[k];
        else {
            int s = col[base + k];
            scv = hs[s] + hdn;
            scv = (scv > 0.f) ? scv : SLOPE * scv;
        }
        float p = expf(scv - mymax);
        if (k < 128) e_[k] = p;
        mysum += p;
    }
    #pragma unroll
    for (int o = 32; o > 0; o >>= 1) mysum += __shfl_xor(mysum, o);
    float inv = 1.f / mysum;

    __syncthreads();   // publish p/col for cross-lane reads

    // phase B: unroll x4, 4 independent h-row loads in flight
    int dl = (d < 128) ? d : 128;
    float accf = 0.f;
    int k = 0;
    for (; k + 4 <= dl; k += 4) {
        int s0 = c_[k], s1 = c_[k+1], s2 = c_[k+2], s3 = c_[k+3];
        float p0 = e_[k], p1 = e_[k+1], p2 = e_[k+2], p3 = e_[k+3];
        float h0 = h[(size_t)s0*64 + lane];
        float h1 = h[(size_t)s1*64 + lane];
        float h2 = h[(size_t)s2*64 + lane];
        float h3 = h[(size_t)s3*64 + lane];
        accf += p0*h0 + p1*h1 + p2*h2 + p3*h3;
    }
    for (; k < dl; ++k) accf += e_[k] * h[(size_t)c_[k]*64 + lane];
    for (; k < d; ++k) {                   // d>128 spill path (never hit at E[deg]=17)
        int s = col[base + k];
        float scv = hs[s] + hdn;
        scv = (scv > 0.f) ? scv : SLOPE * scv;
        accf += expf(scv - mymax) * h[(size_t)s*64 + lane];
    }
    out[n*64 + lane] = fmaxf(accf*inv + bias[lane], 0.f);
}

// ---------------- MLP head: 32 nodes/block, 4x4 tiles, float4 LDS ----------------
__global__ __launch_bounds__(256) void k_mlp(
        const float* __restrict__ xin,
        const float* __restrict__ Wp1, const float* __restrict__ bp1,
        const float* __restrict__ Wp2, const float* __restrict__ bp2,
        float* __restrict__ out) {
    __shared__ float xr[32][64];        // 8 KB
    __shared__ float hid[32][128];      // 16 KB
    __shared__ float wbuf[128*80];      // 40 KB: Wp1 [64][128], then Wp2 padded [128][80]
    int t  = threadIdx.x;
    int nb = blockIdx.x * 32;

    for (int i = t; i < 32*64; i += 256) xr[i >> 6][i & 63] = xin[(size_t)nb*64 + i];
    for (int i = t; i < 64*MLPH; i += 256) wbuf[i] = Wp1[i];    // [k][h]
    __syncthreads();

    // phase 1: hid = relu(x @ Wp1 + bp1); thread = (nq: 4 nodes, hq: 4 hidden)
    {
        int nq = t >> 5;      // 0..7
        int hq = t & 31;      // 0..31
        float acc[4][4];
        #pragma unroll
        for (int hi = 0; hi < 4; ++hi) {
            float bv = bp1[hq*4 + hi];
            #pragma unroll
            for (int ni = 0; ni < 4; ++ni) acc[ni][hi] = bv;
        }
        for (int k = 0; k < 64; k += 4) {
            float4 xv[4];
            #pragma unroll
            for (int ni = 0; ni < 4; ++ni) xv[ni] = *(const float4*)&xr[nq*4+ni][k];
            #pragma unroll
            for (int kk = 0; kk < 4; ++kk) {
                float4 wv = *(const float4*)&wbuf[(k+kk)*MLPH + hq*4];
                #pragma unroll
                for (int ni = 0; ni < 4; ++ni) {
                    float xs = f4get(xv[ni], kk);
                    acc[ni][0] += xs*wv.x; acc[ni][1] += xs*wv.y;
                    acc[ni][2] += xs*wv.z; acc[ni][3] += xs*wv.w;
                }
            }
        }
        #pragma unroll
        for (int ni = 0; ni < 4; ++ni)
            *(float4*)&hid[nq*4+ni][hq*4] = make_float4(
                fmaxf(acc[ni][0], 0.f), fmaxf(acc[ni][1], 0.f),
                fmaxf(acc[ni][2], 0.f), fmaxf(acc[ni][3], 0.f));
    }
    __syncthreads();   // wbuf reads + hid writes complete

    // restage: Wp2 padded to stride 80 ([j][o])
    for (int i = t; i < MLPH*80; i += 256) {
        int jj = i / 80, oo = i % 80;
        wbuf[i] = (oo < ODIM) ? Wp2[jj*ODIM + oo] : 0.f;
    }
    __syncthreads();

    // phase 2: out = hid @ Wp2 + bp2; 152 threads = (8 node-quads x 19 out-quads)
    if (t < 152) {
        int nq2 = t / 19;     // 0..7
        int oq  = t % 19;     // 0..18 (outs oq*4..+3, <74 guarded)
        float acc2[4][4];
        #pragma unroll
        for (int oi = 0; oi < 4; ++oi) {
            int o = oq*4 + oi;
            float bv = (o < ODIM) ? bp2[o] : 0.f;
            #pragma unroll
            for (int ni = 0; ni < 4; ++ni) acc2[ni][oi] = bv;
        }
        for (int j = 0; j < MLPH; j += 4) {
            float4 hv[4];
            #pragma unroll
            for (int ni = 0; ni < 4; ++ni) hv[ni] = *(const float4*)&hid[nq2*4+ni][j];
            #pragma unroll
            for (int jj = 0; jj < 4; ++jj) {
                float4 wv = *(const float4*)&wbuf[(j+jj)*80 + oq*4];
                #pragma unroll
                for (int ni = 0; ni < 4; ++ni) {
                    float hsv = f4get(hv[ni], jj);
                    acc2[ni][0] += hsv*wv.x; acc2[ni][1] += hsv*wv.y;
                    acc2[ni][2] += hsv*wv.z; acc2[ni][3] += hsv*wv.w;
                }
            }
        }
        #pragma unroll
        for (int ni = 0; ni < 4; ++ni)
            #pragma unroll
            for (int oi = 0; oi < 4; ++oi) {
                int o = oq*4 + oi;
                if (o < ODIM) out[(size_t)(nb + nq2*4 + ni)*ODIM + o] = acc2[ni][oi];
            }
    }
}

// ---------------- launch ----------------

extern "C" void kernel_launch(void* const* d_in, const int* in_sizes, int n_in,
                              void* d_out, int out_size, void* d_ws, size_t ws_size,
                              hipStream_t stream) {
    const float* x    = (const float*)d_in[0];
    const int*   ei   = (const int*)  d_in[1];
    const float* W1   = (const float*)d_in[2];
    const float* a1s  = (const float*)d_in[3];
    const float* a1d  = (const float*)d_in[4];
    const float* b1   = (const float*)d_in[5];
    const float* W2   = (const float*)d_in[6];
    const float* a2s  = (const float*)d_in[7];
    const float* a2d  = (const float*)d_in[8];
    const float* b2   = (const float*)d_in[9];
    const float* Wp1  = (const float*)d_in[10];
    const float* bp1  = (const float*)d_in[11];
    const float* Wp2  = (const float*)d_in[12];
    const float* bp2  = (const float*)d_in[13];
    float* out = (float*)d_out;

    const int* esrc = ei;
    const int* edst = ei + EE;

    float* ws   = (float*)d_ws;
    float* bufA = ws;                      // h (N*64)
    float* bufB = bufA + NN*HID;           // layer outputs (N*64)
    float* hs   = bufB + NN*HID;           // N
    float* hd   = hs + NN;                 // N
    int*   deg    = (int*)(hd + NN);       // N
    int*   excl   = deg + NN;              // N  (row begin)
    int*   cursor = excl + NN;             // N  (scatter cursor -> row end)
    int*   partial= cursor + NN;           // 256
    int*   col    = partial + 256;         // ET

    const int EB = (EE + 255) / 256;       // 6250

    // ---- CSR build (shared by both layers) ----
    k_deg_init  <<<(NN+255)/256, 256, 0, stream>>>(deg);
    k_hist      <<<EB, 256, 0, stream>>>(edst, deg);
    k_scan_local<<<NB_SCAN, 512, 0, stream>>>(deg, excl, partial);
    k_scan_part <<<1, 256, 0, stream>>>(partial);
    k_scan_fin  <<<NB_SCAN, 512, 0, stream>>>(excl, partial, cursor, col);
    k_scatter   <<<EB, 256, 0, stream>>>(esrc, edst, cursor, col);

    // ---- GAT layer 1 ----
    k_lin1<<<NN/4, 256, 0, stream>>>(x, W1, a1s, a1d, bufA, hs, hd);
    k_gat <<<NN/4, 256, 0, stream>>>(excl, cursor, col, hs, hd, bufA, b1, bufB);

    // ---- GAT layer 2 ----
    k_lin64<<<NN/32, 128, 0, stream>>>(bufB, W2, a2s, a2d, bufA, hs, hd);
    k_gat  <<<NN/4, 256, 0, stream>>>(excl, cursor, col, hs, hd, bufA, b2, bufB);

    // ---- MLP head ----
    k_mlp<<<NN/32, 256, 0, stream>>>(bufB, Wp1, bp1, Wp2, bp2, out);
}

// Round 5
// 556.305 us; speedup vs baseline: 2.7246x; 1.0710x over previous
//
#include <hip/hip_runtime.h>
#include <math.h>

#define NN   100000
#define EE   1600000
#define ET   (EE + NN)          // edges + self-loops = 1,700,000
#define HID  64
#define MLPH 128
#define ODIM 74
#define SLOPE 0.2f
#define NB_SCAN 196             // ceil(NN/512)

__device__ __forceinline__ float f4get(const float4& v, int i) {
    return i == 0 ? v.x : i == 1 ? v.y : i == 2 ? v.z : v.w;  // unrolled -> constant
}

// ---------------- CSR build (self-loop pre-placed) ----------------

__global__ void k_deg_init(int* __restrict__ deg) {
    int i = blockIdx.x*blockDim.x + threadIdx.x;
    if (i < NN) deg[i] = 1;                     // self-loop
}

__global__ void k_hist(const int* __restrict__ edst, int* __restrict__ deg) {
    int i = blockIdx.x*blockDim.x + threadIdx.x;
    if (i < EE) atomicAdd(&deg[edst[i]], 1);
}

// per-block exclusive scan
__global__ void k_scan_local(const int* __restrict__ deg, int* __restrict__ excl,
                             int* __restrict__ partial) {
    __shared__ int sd[512];
    int g = blockIdx.x*512 + threadIdx.x;
    int v = (g < NN) ? deg[g] : 0;
    sd[threadIdx.x] = v;
    __syncthreads();
    for (int o = 1; o < 512; o <<= 1) {
        int u = (threadIdx.x >= o) ? sd[threadIdx.x - o] : 0;
        __syncthreads();
        sd[threadIdx.x] += u;
        __syncthreads();
    }
    if (g < NN) excl[g] = sd[threadIdx.x] - v;
    if (threadIdx.x == 511) partial[blockIdx.x] = sd[511];
}

__global__ void k_scan_part(int* __restrict__ partial) {
    __shared__ int sp[256];
    int t = threadIdx.x;
    int v = (t < NB_SCAN) ? partial[t] : 0;
    sp[t] = v;
    __syncthreads();
    for (int o = 1; o < 256; o <<= 1) {
        int u = (t >= o) ? sp[t - o] : 0;
        __syncthreads();
        sp[t] += u;
        __syncthreads();
    }
    if (t < NB_SCAN) partial[t] = sp[t];
}

// finalize row starts; write self-loop at row head; cursor points past it
__global__ void k_scan_fin(int* __restrict__ excl, const int* __restrict__ partial,
                           int* __restrict__ cursor, int* __restrict__ col) {
    int g = blockIdx.x*512 + threadIdx.x;
    if (g >= NN) return;
    int off = (blockIdx.x > 0) ? partial[blockIdx.x - 1] : 0;
    int e = excl[g] + off;
    excl[g] = e;
    col[e] = g;                                 // self-loop first in row
    cursor[g] = e + 1;
}

__global__ void k_scatter(const int* __restrict__ esrc, const int* __restrict__ edst,
                          int* __restrict__ cursor, int* __restrict__ col) {
    int i = blockIdx.x*blockDim.x + threadIdx.x;
    if (i >= EE) return;
    int pos = atomicAdd(&cursor[edst[i]], 1);
    col[pos] = esrc[i];
}

// ---------------- dense prologues ----------------

// h = x @ W1 (IN_DIM=3) + hs/hd wave reductions
__global__ void k_lin1(const float* __restrict__ x, const float* __restrict__ W,
                       const float* __restrict__ asrc, const float* __restrict__ adst,
                       float* __restrict__ h, float* __restrict__ hs, float* __restrict__ hd) {
    int node = blockIdx.x * 4 + (threadIdx.x >> 6);
    int f    = threadIdx.x & 63;
    float x0 = x[node*3+0], x1 = x[node*3+1], x2 = x[node*3+2];
    float v  = x0*W[f] + x1*W[64+f] + x2*W[128+f];
    h[node*64+f] = v;
    float ps = v*asrc[f], pd = v*adst[f];
    #pragma unroll
    for (int o = 32; o > 0; o >>= 1) { ps += __shfl_down(ps, o); pd += __shfl_down(pd, o); }
    if (f == 0) { hs[node] = ps; hd[node] = pd; }
}

// h = xin @ W (64x64): 32 nodes/block, 128 threads, 4x4 tile/thread, LDS-staged W
__global__ __launch_bounds__(128) void k_lin64(
        const float* __restrict__ xin, const float* __restrict__ W,
        const float* __restrict__ asrc, const float* __restrict__ adst,
        float* __restrict__ h, float* __restrict__ hs, float* __restrict__ hd) {
    __shared__ float xr[32][64];     // 8 KB (x rows, later reused for h rows)
    __shared__ float wl[64*64];      // 16 KB, [k][o] layout
    int t  = threadIdx.x;
    int nb = blockIdx.x * 32;
    for (int i = t; i < 32*64; i += 128) xr[i >> 6][i & 63] = xin[nb*64 + i];
    for (int i = t; i < 64*64;  i += 128) wl[i] = W[i];
    __syncthreads();

    int nq = t >> 4;    // 0..7 (4 nodes each)
    int hq = t & 15;    // 0..15 (4 outs each)
    float acc[4][4] = {};
    for (int k = 0; k < 64; k += 4) {
        float4 xv[4];
        #pragma unroll
        for (int ni = 0; ni < 4; ++ni) xv[ni] = *(const float4*)&xr[nq*4+ni][k];
        #pragma unroll
        for (int kk = 0; kk < 4; ++kk) {
            float4 wv = *(const float4*)&wl[(k+kk)*64 + hq*4];
            #pragma unroll
            for (int ni = 0; ni < 4; ++ni) {
                float xs = f4get(xv[ni], kk);
                acc[ni][0] += xs*wv.x; acc[ni][1] += xs*wv.y;
                acc[ni][2] += xs*wv.z; acc[ni][3] += xs*wv.w;
            }
        }
    }
    float4 res[4];
    #pragma unroll
    for (int ni = 0; ni < 4; ++ni) {
        res[ni] = make_float4(acc[ni][0], acc[ni][1], acc[ni][2], acc[ni][3]);
        *(float4*)&h[(size_t)(nb + nq*4 + ni)*64 + hq*4] = res[ni];
    }
    __syncthreads();                 // all xr reads done
    #pragma unroll
    for (int ni = 0; ni < 4; ++ni) *(float4*)&xr[nq*4+ni][hq*4] = res[ni];
    __syncthreads();

    // hs/hd: 2 waves x 16 nodes, lane = feature
    int wv_  = t >> 6;
    int lane = t & 63;
    for (int ni = 0; ni < 16; ++ni) {
        int node = wv_*16 + ni;
        float v  = xr[node][lane];
        float ps = v*asrc[lane], pd = v*adst[lane];
        #pragma unroll
        for (int o = 32; o > 0; o >>= 1) { ps += __shfl_down(ps, o); pd += __shfl_down(pd, o); }
        if (lane == 0) { hs[nb+node] = ps; hd[nb+node] = pd; }
    }
}

// ---------------- fused GAT aggregate: one wave per dst node ----------------
__global__ void k_gat(const int* __restrict__ rowbeg, const int* __restrict__ rowend,
                      const int* __restrict__ col,
                      const float* __restrict__ hs, const float* __restrict__ hd,
                      const float* __restrict__ h, const float* __restrict__ bias,
                      float* __restrict__ out) {
    __shared__ float se[4][128];
    __shared__ int   sc[4][128];
    int w    = threadIdx.x >> 6;
    int lane = threadIdx.x & 63;
    int n    = blockIdx.x * 4 + w;
    float* e_ = se[w];
    int*   c_ = sc[w];

    int base = rowbeg[n];
    int d    = rowend[n] - base;          // >=1 (self-loop)
    float hdn = hd[n];

    // phase A1: scores (+ stash col) + wave max
    float mymax = -INFINITY;
    for (int k = lane; k < d; k += 64) {
        int s = col[base + k];
        float scv = hs[s] + hdn;
        scv = (scv > 0.f) ? scv : SLOPE * scv;
        if (k < 128) { e_[k] = scv; c_[k] = s; }
        mymax = fmaxf(mymax, scv);
    }
    #pragma unroll
    for (int o = 32; o > 0; o >>= 1) mymax = fmaxf(mymax, __shfl_xor(mymax, o));

    // phase A2: exp + wave sum (own elements only)
    float mysum = 0.f;
    for (int k = lane; k < d; k += 64) {
        float scv;
        if (k < 128) scv = e_[k];
        else {
            int s = col[base + k];
            scv = hs[s] + hdn;
            scv = (scv > 0.f) ? scv : SLOPE * scv;
        }
        float p = expf(scv - mymax);
        if (k < 128) e_[k] = p;
        mysum += p;
    }
    #pragma unroll
    for (int o = 32; o > 0; o >>= 1) mysum += __shfl_xor(mysum, o);
    float inv = 1.f / mysum;

    __syncthreads();   // publish p/col for cross-lane reads

    // phase B: unroll x4, 4 independent h-row loads in flight
    int dl = (d < 128) ? d : 128;
    float accf = 0.f;
    int k = 0;
    for (; k + 4 <= dl; k += 4) {
        int s0 = c_[k], s1 = c_[k+1], s2 = c_[k+2], s3 = c_[k+3];
        float p0 = e_[k], p1 = e_[k+1], p2 = e_[k+2], p3 = e_[k+3];
        float h0 = h[(size_t)s0*64 + lane];
        float h1 = h[(size_t)s1*64 + lane];
        float h2 = h[(size_t)s2*64 + lane];
        float h3 = h[(size_t)s3*64 + lane];
        accf += p0*h0 + p1*h1 + p2*h2 + p3*h3;
    }
    for (; k < dl; ++k) accf += e_[k] * h[(size_t)c_[k]*64 + lane];
    for (; k < d; ++k) {                   // d>128 spill path (never hit at E[deg]=17)
        int s = col[base + k];
        float scv = hs[s] + hdn;
        scv = (scv > 0.f) ? scv : SLOPE * scv;
        accf += expf(scv - mymax) * h[(size_t)s*64 + lane];
    }
    out[n*64 + lane] = fmaxf(accf*inv + bias[lane], 0.f);
}

// ---------------- MLP head v3: 32 nodes/block, weights from global (L1/L2),
// LDS = xr (8KB) + hid padded to 132 (16.9KB) -> ~25KB, 6 blocks/CU ----------------
__global__ __launch_bounds__(256) void k_mlp(
        const float* __restrict__ xin,
        const float* __restrict__ Wp1, const float* __restrict__ bp1,
        const float* __restrict__ Wp2, const float* __restrict__ bp2,
        float* __restrict__ out) {
    __shared__ float xr[32][64];        // 8 KB
    __shared__ float hid[32][132];      // 16.9 KB; pad->132: broadcast rows on distinct banks
    int t  = threadIdx.x;
    int nb = blockIdx.x * 32;
    int nq = t >> 5;      // 0..7  (4 nodes each)
    int hq = t & 31;      // 0..31 (4 hidden units each in phase 1)

    for (int i = t; i < 32*64; i += 256) xr[i >> 6][i & 63] = xin[(size_t)nb*64 + i];
    __syncthreads();

    // phase 1: hid = relu(x @ Wp1 + bp1); weights streamed from global (coalesced f4)
    {
        float4 bv = *(const float4*)&bp1[hq*4];
        float acc[4][4];
        #pragma unroll
        for (int ni = 0; ni < 4; ++ni) {
            acc[ni][0] = bv.x; acc[ni][1] = bv.y; acc[ni][2] = bv.z; acc[ni][3] = bv.w;
        }
        #pragma unroll 4
        for (int k = 0; k < 64; ++k) {
            float4 wv = *(const float4*)&Wp1[k*MLPH + hq*4];
            float x0 = xr[nq*4+0][k], x1 = xr[nq*4+1][k];
            float x2 = xr[nq*4+2][k], x3 = xr[nq*4+3][k];
            acc[0][0] += x0*wv.x; acc[0][1] += x0*wv.y; acc[0][2] += x0*wv.z; acc[0][3] += x0*wv.w;
            acc[1][0] += x1*wv.x; acc[1][1] += x1*wv.y; acc[1][2] += x1*wv.z; acc[1][3] += x1*wv.w;
            acc[2][0] += x2*wv.x; acc[2][1] += x2*wv.y; acc[2][2] += x2*wv.z; acc[2][3] += x2*wv.w;
            acc[3][0] += x3*wv.x; acc[3][1] += x3*wv.y; acc[3][2] += x3*wv.z; acc[3][3] += x3*wv.w;
        }
        #pragma unroll
        for (int ni = 0; ni < 4; ++ni)
            *(float4*)&hid[nq*4+ni][hq*4] = make_float4(
                fmaxf(acc[ni][0], 0.f), fmaxf(acc[ni][1], 0.f),
                fmaxf(acc[ni][2], 0.f), fmaxf(acc[ni][3], 0.f));
    }
    __syncthreads();

    // phase 2: out = hid @ Wp2 + bp2; thread = (nq: 4 nodes, oq: outs oq, oq+32, oq+64)
    {
        int oq = t & 31;
        bool has3 = (oq + 64) < ODIM;   // oq < 10
        float a0[4], a1[4], a2[4];
        float b0 = bp2[oq], b1v = bp2[oq+32], b2v = has3 ? bp2[oq+64] : 0.f;
        #pragma unroll
        for (int ni = 0; ni < 4; ++ni) { a0[ni] = b0; a1[ni] = b1v; a2[ni] = b2v; }
        #pragma unroll 4
        for (int j = 0; j < MLPH; ++j) {
            float w0 = Wp2[j*ODIM + oq];
            float w1 = Wp2[j*ODIM + oq + 32];
            float w2 = has3 ? Wp2[j*ODIM + oq + 64] : 0.f;
            float h0 = hid[nq*4+0][j], h1 = hid[nq*4+1][j];
            float h2 = hid[nq*4+2][j], h3 = hid[nq*4+3][j];
            a0[0] += h0*w0; a1[0] += h0*w1; a2[0] += h0*w2;
            a0[1] += h1*w0; a1[1] += h1*w1; a2[1] += h1*w2;
            a0[2] += h2*w0; a1[2] += h2*w1; a2[2] += h2*w2;
            a0[3] += h3*w0; a1[3] += h3*w1; a2[3] += h3*w2;
        }
        #pragma unroll
        for (int ni = 0; ni < 4; ++ni) {
            size_t rowo = (size_t)(nb + nq*4 + ni) * ODIM;
            out[rowo + oq]      = a0[ni];
            out[rowo + oq + 32] = a1[ni];
            if (has3) out[rowo + oq + 64] = a2[ni];
        }
    }
}

// ---------------- launch ----------------

extern "C" void kernel_launch(void* const* d_in, const int* in_sizes, int n_in,
                              void* d_out, int out_size, void* d_ws, size_t ws_size,
                              hipStream_t stream) {
    const float* x    = (const float*)d_in[0];
    const int*   ei   = (const int*)  d_in[1];
    const float* W1   = (const float*)d_in[2];
    const float* a1s  = (const float*)d_in[3];
    const float* a1d  = (const float*)d_in[4];
    const float* b1   = (const float*)d_in[5];
    const float* W2   = (const float*)d_in[6];
    const float* a2s  = (const float*)d_in[7];
    const float* a2d  = (const float*)d_in[8];
    const float* b2   = (const float*)d_in[9];
    const float* Wp1  = (const float*)d_in[10];
    const float* bp1  = (const float*)d_in[11];
    const float* Wp2  = (const float*)d_in[12];
    const float* bp2  = (const float*)d_in[13];
    float* out = (float*)d_out;

    const int* esrc = ei;
    const int* edst = ei + EE;

    float* ws   = (float*)d_ws;
    float* bufA = ws;                      // h (N*64)
    float* bufB = bufA + NN*HID;           // layer outputs (N*64)
    float* hs   = bufB + NN*HID;           // N
    float* hd   = hs + NN;                 // N
    int*   deg    = (int*)(hd + NN);       // N
    int*   excl   = deg + NN;              // N  (row begin)
    int*   cursor = excl + NN;             // N  (scatter cursor -> row end)
    int*   partial= cursor + NN;           // 256
    int*   col    = partial + 256;         // ET

    const int EB = (EE + 255) / 256;       // 6250

    // ---- CSR build (shared by both layers) ----
    k_deg_init  <<<(NN+255)/256, 256, 0, stream>>>(deg);
    k_hist      <<<EB, 256, 0, stream>>>(edst, deg);
    k_scan_local<<<NB_SCAN, 512, 0, stream>>>(deg, excl, partial);
    k_scan_part <<<1, 256, 0, stream>>>(partial);
    k_scan_fin  <<<NB_SCAN, 512, 0, stream>>>(excl, partial, cursor, col);
    k_scatter   <<<EB, 256, 0, stream>>>(esrc, edst, cursor, col);

    // ---- GAT layer 1 ----
    k_lin1<<<NN/4, 256, 0, stream>>>(x, W1, a1s, a1d, bufA, hs, hd);
    k_gat <<<NN/4, 256, 0, stream>>>(excl, cursor, col, hs, hd, bufA, b1, bufB);

    // ---- GAT layer 2 ----
    k_lin64<<<NN/32, 128, 0, stream>>>(bufB, W2, a2s, a2d, bufA, hs, hd);
    k_gat  <<<NN/4, 256, 0, stream>>>(excl, cursor, col, hs, hd, bufA, b2, bufB);

    // ---- MLP head ----
    k_mlp<<<NN/32, 256, 0, stream>>>(bufB, Wp1, bp1, Wp2, bp2, out);
}

// Round 6
// 404.137 us; speedup vs baseline: 3.7504x; 1.3765x over previous
//
#include <hip/hip_runtime.h>
#include <math.h>

#define NN   100000
#define EE   1600000
#define ET   (EE + NN)          // edges + self-loops = 1,700,000
#define HID  64
#define MLPH 128
#define ODIM 74
#define SLOPE 0.2f

#define NB   196                // coarse buckets of 512 nodes (dst >> 9)
#define GA   800                // pass-A blocks
#define EPB  (EE / GA)          // 2000 edges per pass-A block

__device__ __forceinline__ float f4get(const float4& v, int i) {
    return i == 0 ? v.x : i == 1 ? v.y : i == 2 ? v.z : v.w;  // unrolled -> constant
}

// ================= CSR build: bucketed counting sort, no global atomics =================

// Pass A1: per-block LDS histogram over 196 coarse buckets
__global__ void k_partA_hist(const int* __restrict__ edst, int* __restrict__ M) {
    __shared__ int hist[NB];
    int t = threadIdx.x;
    if (t < NB) hist[t] = 0;
    __syncthreads();
    int base = blockIdx.x * EPB;
    for (int i = t; i < EPB; i += 256)
        atomicAdd(&hist[edst[base + i] >> 9], 1);
    __syncthreads();
    if (t < NB) M[blockIdx.x * NB + t] = hist[t];
}

// scan each bucket-column over the GA blocks: colExcl[b,k] = sum_{b'<b} M[b',k]; colsum[k]=total
__global__ void k_scan_col(const int* __restrict__ M, int* __restrict__ colExcl,
                           int* __restrict__ colsum) {
    __shared__ int sd[256];
    __shared__ int carry;
    int k = blockIdx.x, t = threadIdx.x;
    if (t == 0) carry = 0;
    __syncthreads();
    for (int c = 0; c < GA; c += 256) {
        int v = (c + t < GA) ? M[(c + t) * NB + k] : 0;
        sd[t] = v;
        __syncthreads();
        for (int o = 1; o < 256; o <<= 1) {
            int u = (t >= o) ? sd[t - o] : 0;
            __syncthreads();
            sd[t] += u;
            __syncthreads();
        }
        if (c + t < GA) colExcl[(c + t) * NB + k] = carry + sd[t] - v;
        __syncthreads();
        if (t == 255) carry += sd[255];
        __syncthreads();
    }
    if (t == 0) colsum[k] = carry;
}

// exclusive scan of the 196 bucket totals
__global__ void k_scan_bkt(const int* __restrict__ colsum, int* __restrict__ bucketBase) {
    __shared__ int sd[256];
    int t = threadIdx.x;
    int v = (t < NB) ? colsum[t] : 0;
    sd[t] = v;
    __syncthreads();
    for (int o = 1; o < 256; o <<= 1) {
        int u = (t >= o) ? sd[t - o] : 0;
        __syncthreads();
        sd[t] += u;
        __syncthreads();
    }
    if (t < NB) bucketBase[t] = sd[t] - v;
    if (t == NB - 1) bucketBase[NB] = sd[t];
}

// Pass A2: scatter packed (dst,src) into bucket-partitioned tmp via LDS cursors
__global__ void k_partA_scat(const int* __restrict__ esrc, const int* __restrict__ edst,
                             const int* __restrict__ colExcl, const int* __restrict__ bucketBase,
                             unsigned long long* __restrict__ tmp) {
    __shared__ int cur[NB];
    int t = threadIdx.x;
    if (t < NB) cur[t] = bucketBase[t] + colExcl[blockIdx.x * NB + t];
    __syncthreads();
    int base = blockIdx.x * EPB;
    for (int i = t; i < EPB; i += 256) {
        int s = esrc[base + i], d = edst[base + i];
        int pos = atomicAdd(&cur[d >> 9], 1);
        tmp[pos] = ((unsigned long long)(unsigned)d << 32) | (unsigned)s;
    }
}

// Pass B: one block per bucket — LDS deg hist + LDS scan + LDS-cursor scatter into col;
// emits rowbeg/rowend with self-loop pre-placed at each row head.
__global__ __launch_bounds__(512) void k_partB(
        const unsigned long long* __restrict__ tmp, const int* __restrict__ bucketBase,
        int* __restrict__ rowbeg, int* __restrict__ rowend, int* __restrict__ col) {
    __shared__ int deg[512];
    __shared__ int rb[512];
    __shared__ int cur[512];
    int k = blockIdx.x, t = threadIdx.x;
    int lo = bucketBase[k], hi = bucketBase[k + 1];
    int nodeBase = k << 9;
    int nNodes = (NN - nodeBase < 512) ? (NN - nodeBase) : 512;

    deg[t] = 0;
    __syncthreads();
    for (int i = lo + t; i < hi; i += 512)
        atomicAdd(&deg[(int)(tmp[i] >> 32) - nodeBase], 1);
    __syncthreads();

    // exclusive scan over (deg + 1 self-loop) for the bucket's nodes
    int v = (t < nNodes) ? deg[t] + 1 : 0;
    rb[t] = v;
    __syncthreads();
    for (int o = 1; o < 512; o <<= 1) {
        int u = (t >= o) ? rb[t - o] : 0;
        __syncthreads();
        rb[t] += u;
        __syncthreads();
    }
    // global col segment for bucket k starts at bucketBase[k] + (#self-loops before) = nodeBase
    int myBeg = lo + nodeBase + rb[t] - v;
    if (t < nNodes) {
        int g = nodeBase + t;
        rowbeg[g] = myBeg;
        rowend[g] = myBeg + deg[t] + 1;
        col[myBeg] = g;              // self-loop first in row
        cur[t] = myBeg + 1;
    }
    __syncthreads();
    for (int i = lo + t; i < hi; i += 512) {
        unsigned long long e = tmp[i];
        int dLow = (int)(e >> 32) - nodeBase;
        int pos = atomicAdd(&cur[dLow], 1);
        col[pos] = (int)(e & 0xffffffffu);
    }
}

// ---------------- dense prologues ----------------

// h = x @ W1 (IN_DIM=3) + hs/hd wave reductions
__global__ void k_lin1(const float* __restrict__ x, const float* __restrict__ W,
                       const float* __restrict__ asrc, const float* __restrict__ adst,
                       float* __restrict__ h, float* __restrict__ hs, float* __restrict__ hd) {
    int node = blockIdx.x * 4 + (threadIdx.x >> 6);
    int f    = threadIdx.x & 63;
    float x0 = x[node*3+0], x1 = x[node*3+1], x2 = x[node*3+2];
    float v  = x0*W[f] + x1*W[64+f] + x2*W[128+f];
    h[node*64+f] = v;
    float ps = v*asrc[f], pd = v*adst[f];
    #pragma unroll
    for (int o = 32; o > 0; o >>= 1) { ps += __shfl_down(ps, o); pd += __shfl_down(pd, o); }
    if (f == 0) { hs[node] = ps; hd[node] = pd; }
}

// h = xin @ W (64x64): 32 nodes/block, 128 threads, 4x4 tile/thread, LDS-staged W
__global__ __launch_bounds__(128) void k_lin64(
        const float* __restrict__ xin, const float* __restrict__ W,
        const float* __restrict__ asrc, const float* __restrict__ adst,
        float* __restrict__ h, float* __restrict__ hs, float* __restrict__ hd) {
    __shared__ float xr[32][64];     // 8 KB (x rows, later reused for h rows)
    __shared__ float wl[64*64];      // 16 KB, [k][o] layout
    int t  = threadIdx.x;
    int nb = blockIdx.x * 32;
    for (int i = t; i < 32*64; i += 128) xr[i >> 6][i & 63] = xin[nb*64 + i];
    for (int i = t; i < 64*64;  i += 128) wl[i] = W[i];
    __syncthreads();

    int nq = t >> 4;    // 0..7 (4 nodes each)
    int hq = t & 15;    // 0..15 (4 outs each)
    float acc[4][4] = {};
    for (int k = 0; k < 64; k += 4) {
        float4 xv[4];
        #pragma unroll
        for (int ni = 0; ni < 4; ++ni) xv[ni] = *(const float4*)&xr[nq*4+ni][k];
        #pragma unroll
        for (int kk = 0; kk < 4; ++kk) {
            float4 wv = *(const float4*)&wl[(k+kk)*64 + hq*4];
            #pragma unroll
            for (int ni = 0; ni < 4; ++ni) {
                float xs = f4get(xv[ni], kk);
                acc[ni][0] += xs*wv.x; acc[ni][1] += xs*wv.y;
                acc[ni][2] += xs*wv.z; acc[ni][3] += xs*wv.w;
            }
        }
    }
    float4 res[4];
    #pragma unroll
    for (int ni = 0; ni < 4; ++ni) {
        res[ni] = make_float4(acc[ni][0], acc[ni][1], acc[ni][2], acc[ni][3]);
        *(float4*)&h[(size_t)(nb + nq*4 + ni)*64 + hq*4] = res[ni];
    }
    __syncthreads();                 // all xr reads done
    #pragma unroll
    for (int ni = 0; ni < 4; ++ni) *(float4*)&xr[nq*4+ni][hq*4] = res[ni];
    __syncthreads();

    // hs/hd: 2 waves x 16 nodes, lane = feature
    int wv_  = t >> 6;
    int lane = t & 63;
    for (int ni = 0; ni < 16; ++ni) {
        int node = wv_*16 + ni;
        float v  = xr[node][lane];
        float ps = v*asrc[lane], pd = v*adst[lane];
        #pragma unroll
        for (int o = 32; o > 0; o >>= 1) { ps += __shfl_down(ps, o); pd += __shfl_down(pd, o); }
        if (lane == 0) { hs[nb+node] = ps; hd[nb+node] = pd; }
    }
}

// ---------------- fused GAT aggregate: one wave per dst node ----------------
__global__ void k_gat(const int* __restrict__ rowbeg, const int* __restrict__ rowend,
                      const int* __restrict__ col,
                      const float* __restrict__ hs, const float* __restrict__ hd,
                      const float* __restrict__ h, const float* __restrict__ bias,
                      float* __restrict__ out) {
    __shared__ float se[4][128];
    __shared__ int   sc[4][128];
    int w    = threadIdx.x >> 6;
    int lane = threadIdx.x & 63;
    int n    = blockIdx.x * 4 + w;
    float* e_ = se[w];
    int*   c_ = sc[w];

    int base = rowbeg[n];
    int d    = rowend[n] - base;          // >=1 (self-loop)
    float hdn = hd[n];

    // phase A1: scores (+ stash col) + wave max
    float mymax = -INFINITY;
    for (int k = lane; k < d; k += 64) {
        int s = col[base + k];
        float scv = hs[s] + hdn;
        scv = (scv > 0.f) ? scv : SLOPE * scv;
        if (k < 128) { e_[k] = scv; c_[k] = s; }
        mymax = fmaxf(mymax, scv);
    }
    #pragma unroll
    for (int o = 32; o > 0; o >>= 1) mymax = fmaxf(mymax, __shfl_xor(mymax, o));

    // phase A2: exp + wave sum (own elements only)
    float mysum = 0.f;
    for (int k = lane; k < d; k += 64) {
        float scv;
        if (k < 128) scv = e_[k];
        else {
            int s = col[base + k];
            scv = hs[s] + hdn;
            scv = (scv > 0.f) ? scv : SLOPE * scv;
        }
        float p = expf(scv - mymax);
        if (k < 128) e_[k] = p;
        mysum += p;
    }
    #pragma unroll
    for (int o = 32; o > 0; o >>= 1) mysum += __shfl_xor(mysum, o);
    float inv = 1.f / mysum;

    __syncthreads();   // publish p/col for cross-lane reads

    // phase B: unroll x4, 4 independent h-row loads in flight
    int dl = (d < 128) ? d : 128;
    float accf = 0.f;
    int k = 0;
    for (; k + 4 <= dl; k += 4) {
        int s0 = c_[k], s1 = c_[k+1], s2 = c_[k+2], s3 = c_[k+3];
        float p0 = e_[k], p1 = e_[k+1], p2 = e_[k+2], p3 = e_[k+3];
        float h0 = h[(size_t)s0*64 + lane];
        float h1 = h[(size_t)s1*64 + lane];
        float h2 = h[(size_t)s2*64 + lane];
        float h3 = h[(size_t)s3*64 + lane];
        accf += p0*h0 + p1*h1 + p2*h2 + p3*h3;
    }
    for (; k < dl; ++k) accf += e_[k] * h[(size_t)c_[k]*64 + lane];
    for (; k < d; ++k) {                   // d>128 spill path (never hit at E[deg]=17)
        int s = col[base + k];
        float scv = hs[s] + hdn;
        scv = (scv > 0.f) ? scv : SLOPE * scv;
        accf += expf(scv - mymax) * h[(size_t)s*64 + lane];
    }
    out[n*64 + lane] = fmaxf(accf*inv + bias[lane], 0.f);
}

// ---------------- MLP head v3: 32 nodes/block, weights from global (L1/L2) ----------------
__global__ __launch_bounds__(256) void k_mlp(
        const float* __restrict__ xin,
        const float* __restrict__ Wp1, const float* __restrict__ bp1,
        const float* __restrict__ Wp2, const float* __restrict__ bp2,
        float* __restrict__ out) {
    __shared__ float xr[32][64];        // 8 KB
    __shared__ float hid[32][132];      // 16.9 KB; pad->132: broadcast rows on distinct banks
    int t  = threadIdx.x;
    int nb = blockIdx.x * 32;
    int nq = t >> 5;      // 0..7  (4 nodes each)
    int hq = t & 31;      // 0..31 (4 hidden units each in phase 1)

    for (int i = t; i < 32*64; i += 256) xr[i >> 6][i & 63] = xin[(size_t)nb*64 + i];
    __syncthreads();

    // phase 1: hid = relu(x @ Wp1 + bp1); weights streamed from global (coalesced f4)
    {
        float4 bv = *(const float4*)&bp1[hq*4];
        float acc[4][4];
        #pragma unroll
        for (int ni = 0; ni < 4; ++ni) {
            acc[ni][0] = bv.x; acc[ni][1] = bv.y; acc[ni][2] = bv.z; acc[ni][3] = bv.w;
        }
        #pragma unroll 4
        for (int k = 0; k < 64; ++k) {
            float4 wv = *(const float4*)&Wp1[k*MLPH + hq*4];
            float x0 = xr[nq*4+0][k], x1 = xr[nq*4+1][k];
            float x2 = xr[nq*4+2][k], x3 = xr[nq*4+3][k];
            acc[0][0] += x0*wv.x; acc[0][1] += x0*wv.y; acc[0][2] += x0*wv.z; acc[0][3] += x0*wv.w;
            acc[1][0] += x1*wv.x; acc[1][1] += x1*wv.y; acc[1][2] += x1*wv.z; acc[1][3] += x1*wv.w;
            acc[2][0] += x2*wv.x; acc[2][1] += x2*wv.y; acc[2][2] += x2*wv.z; acc[2][3] += x2*wv.w;
            acc[3][0] += x3*wv.x; acc[3][1] += x3*wv.y; acc[3][2] += x3*wv.z; acc[3][3] += x3*wv.w;
        }
        #pragma unroll
        for (int ni = 0; ni < 4; ++ni)
            *(float4*)&hid[nq*4+ni][hq*4] = make_float4(
                fmaxf(acc[ni][0], 0.f), fmaxf(acc[ni][1], 0.f),
                fmaxf(acc[ni][2], 0.f), fmaxf(acc[ni][3], 0.f));
    }
    __syncthreads();

    // phase 2: out = hid @ Wp2 + bp2; thread = (nq: 4 nodes, oq: outs oq, oq+32, oq+64)
    {
        int oq = t & 31;
        bool has3 = (oq + 64) < ODIM;   // oq < 10
        float a0[4], a1[4], a2[4];
        float b0 = bp2[oq], b1v = bp2[oq+32], b2v = has3 ? bp2[oq+64] : 0.f;
        #pragma unroll
        for (int ni = 0; ni < 4; ++ni) { a0[ni] = b0; a1[ni] = b1v; a2[ni] = b2v; }
        #pragma unroll 4
        for (int j = 0; j < MLPH; ++j) {
            float w0 = Wp2[j*ODIM + oq];
            float w1 = Wp2[j*ODIM + oq + 32];
            float w2 = has3 ? Wp2[j*ODIM + oq + 64] : 0.f;
            float h0 = hid[nq*4+0][j], h1 = hid[nq*4+1][j];
            float h2 = hid[nq*4+2][j], h3 = hid[nq*4+3][j];
            a0[0] += h0*w0; a1[0] += h0*w1; a2[0] += h0*w2;
            a0[1] += h1*w0; a1[1] += h1*w1; a2[1] += h1*w2;
            a0[2] += h2*w0; a1[2] += h2*w1; a2[2] += h2*w2;
            a0[3] += h3*w0; a1[3] += h3*w1; a2[3] += h3*w2;
        }
        #pragma unroll
        for (int ni = 0; ni < 4; ++ni) {
            size_t rowo = (size_t)(nb + nq*4 + ni) * ODIM;
            out[rowo + oq]      = a0[ni];
            out[rowo + oq + 32] = a1[ni];
            if (has3) out[rowo + oq + 64] = a2[ni];
        }
    }
}

// ---------------- launch ----------------

extern "C" void kernel_launch(void* const* d_in, const int* in_sizes, int n_in,
                              void* d_out, int out_size, void* d_ws, size_t ws_size,
                              hipStream_t stream) {
    const float* x    = (const float*)d_in[0];
    const int*   ei   = (const int*)  d_in[1];
    const float* W1   = (const float*)d_in[2];
    const float* a1s  = (const float*)d_in[3];
    const float* a1d  = (const float*)d_in[4];
    const float* b1   = (const float*)d_in[5];
    const float* W2   = (const float*)d_in[6];
    const float* a2s  = (const float*)d_in[7];
    const float* a2d  = (const float*)d_in[8];
    const float* b2   = (const float*)d_in[9];
    const float* Wp1  = (const float*)d_in[10];
    const float* bp1  = (const float*)d_in[11];
    const float* Wp2  = (const float*)d_in[12];
    const float* bp2  = (const float*)d_in[13];
    float* out = (float*)d_out;

    const int* esrc = ei;
    const int* edst = ei + EE;

    float* ws   = (float*)d_ws;
    float* bufA = ws;                      // h (N*64); first 12.8MB overlaid by tmp during CSR build
    float* bufB = bufA + NN*HID;           // layer outputs (N*64)
    float* hs   = bufB + NN*HID;           // N
    float* hd   = hs + NN;                 // N
    int* rowbeg = (int*)(hd + NN);         // N
    int* rowend = rowbeg + NN;             // N
    int* col    = rowend + NN;             // ET
    int* M      = col + ET;                // GA*NB
    int* colExcl= M + GA*NB;               // GA*NB
    int* colsum = colExcl + GA*NB;         // NB
    int* bucketBase = colsum + NB;         // NB+1
    unsigned long long* tmp = (unsigned long long*)bufA;   // EE packed records (12.8MB)

    // ---- CSR build (no global atomics; shared by both layers) ----
    k_partA_hist<<<GA, 256, 0, stream>>>(edst, M);
    k_scan_col  <<<NB, 256, 0, stream>>>(M, colExcl, colsum);
    k_scan_bkt  <<<1, 256, 0, stream>>>(colsum, bucketBase);
    k_partA_scat<<<GA, 256, 0, stream>>>(esrc, edst, colExcl, bucketBase, tmp);
    k_partB     <<<NB, 512, 0, stream>>>(tmp, bucketBase, rowbeg, rowend, col);

    // ---- GAT layer 1 (k_lin1 writes bufA after tmp is consumed; stream-ordered) ----
    k_lin1<<<NN/4, 256, 0, stream>>>(x, W1, a1s, a1d, bufA, hs, hd);
    k_gat <<<NN/4, 256, 0, stream>>>(rowbeg, rowend, col, hs, hd, bufA, b1, bufB);

    // ---- GAT layer 2 ----
    k_lin64<<<NN/32, 128, 0, stream>>>(bufB, W2, a2s, a2d, bufA, hs, hd);
    k_gat  <<<NN/4, 256, 0, stream>>>(rowbeg, rowend, col, hs, hd, bufA, b2, bufB);

    // ---- MLP head ----
    k_mlp<<<NN/32, 256, 0, stream>>>(bufB, Wp1, bp1, Wp2, bp2, out);
}